// Round 3
// baseline (85.953 us; speedup 1.0000x reference)
//
#include <hip/hip_runtime.h>
#include <stdint.h>

#define BATCH 256
#define INF   1024
#define OUTF  128
#define KD    8
#define NN    1024      // OUTF*KD
#define OROW  1152      // INF + OUTF

// K1 LDS geometry (per K-chunk of 64):
//  x chunk: 32 rows x 64 f32 = 8 KB, packed, seg^row XOR applied on GLOBAL src
//  T chunk: 64 k-rows x 32 f32 = 8 KB in 8 DMA blocks of 1 KB placed at
//           stride 264 dwords (+32B pad) so b32 column reads are 2-way (free)
#define XCHW 2048       // dwords per x chunk
#define TCHW 2112       // dwords per T chunk (8 * 264)

typedef __attribute__((ext_vector_type(8))) short short8;
typedef __attribute__((ext_vector_type(4))) float f32x4;

__device__ __forceinline__ unsigned short f2bf(float f) {
    union { float f; uint32_t u; } v; v.f = f;
    uint32_t r = v.u + 0x7FFFu + ((v.u >> 16) & 1u);   // RNE
    return (unsigned short)(r >> 16);
}

// Stage K-chunk c of this block's x-tile (32 rows) and T-tile (32 cols) via DMA.
// 4 instrs per wave: 2 x-instrs (1 KB = 4 rows x 256 B) + 2 T-instrs (1 KB = 8 k-rows x 128 B).
__device__ __forceinline__ void stage_xt(
    const float* __restrict__ x, const float* __restrict__ T,
    float* xbuf, float* tbuf, int a0, int n0, int c, int wave, int lane)
{
    {   // x: dest (instr i, lane l) -> row i*4 + (l>>4), seg l&15; src seg XOR'd by row&7
        const int r = lane >> 4, seg = lane & 15;
        #pragma unroll
        for (int p = 0; p < 2; ++p) {
            const int i = wave * 2 + p;
            const int row = i * 4 + r;
            const int segS = seg ^ (row & 7);
            const float* src = x + (size_t)(a0 + row) * INF + c * 64 + segS * 4;
            float* dst = xbuf + i * 256;
            __builtin_amdgcn_global_load_lds(
                (const __attribute__((address_space(1))) unsigned int*)src,
                (__attribute__((address_space(3))) unsigned int*)dst, 16, 0, 0);
        }
    }
    {   // T: dest block i at i*264 dwords; row k = i*8 + (l>>3), seg l&7 (16 B of n)
        const int kr = lane >> 3, seg = lane & 7;
        #pragma unroll
        for (int p = 0; p < 2; ++p) {
            const int i = wave * 2 + p;
            const int k = i * 8 + kr;
            const float* src = T + (size_t)(c * 64 + k) * NN + n0 + seg * 4;
            float* dst = tbuf + i * 264;
            __builtin_amdgcn_global_load_lds(
                (const __attribute__((address_space(1))) unsigned int*)src,
                (__attribute__((address_space(3))) unsigned int*)dst, 16, 0, 0);
        }
    }
}

// K1: M = x @ T  (256x1024), written into out's x-region (exactly 1 MB scratch).
// 256 blocks = 8 a-tiles x 32 n-tiles of 32x32. 4 waves; wave (h,g) owns 16x16 quadrant.
// Triple-buffered DMA pipeline, counted vmcnt(4), raw barrier (round-2-proven structure).
__global__ __launch_bounds__(256, 2) void gemm_kernel(
    const float* __restrict__ x, const float* __restrict__ T,
    float* __restrict__ out)
{
    __shared__ __align__(16) float xls[3 * XCHW];   // 24 KB
    __shared__ __align__(16) float tls[3 * TCHW];   // 25.3 KB

    const int bid = blockIdx.x;
    const int a0 = (bid & 7) << 5;
    const int n0 = (bid >> 3) << 5;
    const int t = threadIdx.x, wave = t >> 6, lane = t & 63;
    const int rc = lane & 15, quad = lane >> 4;
    const int h = wave >> 1, g = wave & 1;
    const int rloc = h * 16 + rc;       // x row within tile
    const int r7 = rc & 7;
    const int cn = g * 16 + rc;         // T col within tile

    stage_xt(x, T, xls, tls, a0, n0, 0, wave, lane);
    stage_xt(x, T, xls + XCHW, tls + TCHW, a0, n0, 1, wave, lane);

    f32x4 acc = {0.f, 0.f, 0.f, 0.f};

    for (int c = 0; c < 16; ++c) {
        if (c == 15) { asm volatile("s_waitcnt vmcnt(0)" ::: "memory"); }
        else         { asm volatile("s_waitcnt vmcnt(4)" ::: "memory"); }
        __builtin_amdgcn_sched_barrier(0);
        __builtin_amdgcn_s_barrier();
        if (c + 2 < 16)
            stage_xt(x, T, xls + ((c + 2) % 3) * XCHW, tls + ((c + 2) % 3) * TCHW,
                     a0, n0, c + 2, wave, lane);
        const float* xc = xls + (c % 3) * XCHW;
        const float* tc = tls + (c % 3) * TCHW;
        #pragma unroll
        for (int ks = 0; ks < 2; ++ks) {
            // A frag: row rloc, k = ks*32 + quad*8 .. +8 (two XOR-swizzled b128 reads)
            f32x4 av0 = *(const f32x4*)(xc + rloc * 64 + (((ks * 8 + quad * 2 + 0) ^ r7) << 2));
            f32x4 av1 = *(const f32x4*)(xc + rloc * 64 + (((ks * 8 + quad * 2 + 1) ^ r7) << 2));
            // B frag: col cn, k = ks*32 + quad*8 + j (8x b32, 2-way banks via +32B pad)
            float bv[8];
            #pragma unroll
            for (int j = 0; j < 8; ++j)
                bv[j] = tc[(ks * 4 + quad) * 264 + j * 32 + cn];
            short8 af, bf;
            af[0] = (short)f2bf(av0[0]); af[1] = (short)f2bf(av0[1]);
            af[2] = (short)f2bf(av0[2]); af[3] = (short)f2bf(av0[3]);
            af[4] = (short)f2bf(av1[0]); af[5] = (short)f2bf(av1[1]);
            af[6] = (short)f2bf(av1[2]); af[7] = (short)f2bf(av1[3]);
            #pragma unroll
            for (int j = 0; j < 8; ++j) bf[j] = (short)f2bf(bv[j]);
            acc = __builtin_amdgcn_mfma_f32_16x16x32_bf16(af, bf, acc, 0, 0, 0);
        }
    }

    // C/D layout: col = lane&15, row = quad*4 + r  [m89/m91]
    #pragma unroll
    for (int r = 0; r < 4; ++r)
        out[(size_t)(a0 + h * 16 + quad * 4 + r) * OROW + (n0 + g * 16 + rc)] = acc[r];
}

// K2: 256 blocks = (o, a-half). Reads the block-private 8 KB slice M[:, 8o..8o+8)
// from out's x-region into LDS, computes c[a][o] for its 128 a's over ALL b, writes
// c directly (no atomics). M columns are partitioned by o -> no cross-block hazard.
__global__ __launch_bounds__(256, 4) void pair_kernel(
    const float* __restrict__ Msrc, float* __restrict__ out)
{
    __shared__ __align__(16) float Mloc[256 * 12];
    __shared__ float red[256];
    const int o = blockIdx.x >> 1;
    const int ha = blockIdx.x & 1;
    const int t = threadIdx.x;

    {   // thread t loads M row t, 8 floats
        const float* src = Msrc + (size_t)t * OROW + o * 8;
        f32x4 v0 = *(const f32x4*)(src);
        f32x4 v1 = *(const f32x4*)(src + 4);
        *(f32x4*)(Mloc + t * 12) = v0;
        *(f32x4*)(Mloc + t * 12 + 4) = v1;
    }
    __syncthreads();

    const int ai = t & 127, hb = t >> 7;          // hb wave-uniform -> broadcast reads
    const int a = ha * 128 + ai;
    f32x4 m0 = *(const f32x4*)(Mloc + a * 12);
    f32x4 m1 = *(const f32x4*)(Mloc + a * 12 + 4);
    float ssum = 0.f;
    #pragma unroll 4
    for (int j = 0; j < 128; ++j) {
        const float* mb = Mloc + (hb * 128 + j) * 12;
        f32x4 q0 = *(const f32x4*)(mb);
        f32x4 q1 = *(const f32x4*)(mb + 4);
        float d = fabsf(m0[0] - q0[0]) + fabsf(m0[1] - q0[1])
                + fabsf(m0[2] - q0[2]) + fabsf(m0[3] - q0[3])
                + fabsf(m1[0] - q1[0]) + fabsf(m1[1] - q1[1])
                + fabsf(m1[2] - q1[2]) + fabsf(m1[3] - q1[3]);
        ssum += __expf(-d);
    }
    red[t] = ssum;
    __syncthreads();
    if (t < 128)   // self term exp(0)=1 cancelled by -1
        out[(size_t)(ha * 128 + t) * OROW + INF + o] = red[t] + red[t + 128] - 1.0f;
}

// K3: restore x into out's x-region. Runs after K2 (stream order), so all M reads done.
__global__ __launch_bounds__(256) void copy_kernel(
    const float* __restrict__ x, float* __restrict__ out)
{
    const int bx = blockIdx.x, t = threadIdx.x;
    #pragma unroll
    for (int p = 0; p < 4; ++p) {
        const int a = bx * 4 + p;
        const int j = t * 4;
        float4 v = *(const float4*)(x + (size_t)a * INF + j);
        *(float4*)(out + (size_t)a * OROW + j) = v;
    }
}

extern "C" void kernel_launch(void* const* d_in, const int* in_sizes, int n_in,
                              void* d_out, int out_size, void* d_ws, size_t ws_size,
                              hipStream_t stream) {
    const float* x = (const float*)d_in[0];
    const float* T = (const float*)d_in[1];
    float* out = (float*)d_out;
    (void)d_ws; (void)ws_size;   // NO workspace use: tests the re-poison-fill hypothesis

    gemm_kernel<<<256, 256, 0, stream>>>(x, T, out);   // M -> out x-region
    pair_kernel<<<256, 256, 0, stream>>>(out, out);    // c -> out c-region
    copy_kernel<<<64, 256, 0, stream>>>(x, out);       // x -> out x-region
}